// Round 1
// baseline (1541.517 us; speedup 1.0000x reference)
//
#include <hip/hip_runtime.h>
#include <hip/hip_bf16.h>

#define NRAYS 4096
#define NS 256
#define G 160
#define G2 (160*160)
#define G3 (160*160*160)
#define K0DIM 12
#define WIDTH 128
#define CHUNK 32
#define NCHUNK 8
#define HBS 136              // h0B bf16 row stride (272 B: 16B-aligned rows, 2-way banks = free)
#define ACT_SHIFT_F (-4.5951198501345889f)
#define TNEAR 0.2f
#define TFAR 1.8f

// workspace layout: [0] mode (int); +1024: W1G frag table (32768 B); +33792: W0G (4096 B)
#define WS_W1G_OFF 1024
#define WS_W0G_OFF (1024 + 32768)

typedef unsigned short u16;
typedef unsigned int u32;
typedef __attribute__((ext_vector_type(8))) short short8;   // 8 bf16 = 4 VGPRs (MFMA A/B frag)
typedef __attribute__((ext_vector_type(4))) float floatx4;  // MFMA C/D frag

// W1G[kq][qsub][col][j]: B-frag for (kq, quarter qsub, output col) = 16 contiguous bytes
#define W1F_IDX(kq, qs, n) (((((kq)<<2) + (qs)) * 128 + (n)) << 3)

__device__ __forceinline__ float bf2f(u16 u) {
    union { u32 i; float f; } v; v.i = ((u32)u) << 16; return v.f;
}
__device__ __forceinline__ u16 f2bf(float f) {   // RTNE fp32 -> bf16
    union { float f; u32 u; } v; v.f = f;
    u32 r = v.u + 0x7FFFu + ((v.u >> 16) & 1u);
    return (u16)(r >> 16);
}

__device__ __forceinline__ float loadv(const float* p, int i) { return p[i]; }
__device__ __forceinline__ float loadv(const u16* p, int i)   { return bf2f(p[i]); }
__device__ __forceinline__ void storev(float* p, int i, float v) { p[i] = v; }
__device__ __forceinline__ void storev(u16* p, int i, float v)   { p[i] = f2bf(v); }

// z-quad raw vector type per dtype
template <typename T> struct QT;
template <> struct QT<u16>   { using type = ushort4; };
template <> struct QT<float> { using type = float4;  };

// select values at (z0, z0+1) = quad[d], quad[d+1], d in {0,1,2}
__device__ __forceinline__ void zpair(const ushort4& q, int d, float& v0, float& v1) {
    u16 r0 = (d == 0) ? q.x : ((d == 1) ? q.y : q.z);
    u16 r1 = (d == 0) ? q.y : ((d == 1) ? q.z : q.w);
    v0 = bf2f(r0); v1 = bf2f(r1);
}
__device__ __forceinline__ void zpair(const float4& q, int d, float& v0, float& v1) {
    v0 = (d == 0) ? q.x : ((d == 1) ? q.y : q.z);
    v1 = (d == 0) ? q.y : ((d == 1) ? q.z : q.w);
}

struct CoordsE { int base; int d; float fx, fy, fz; };

__device__ __forceinline__ CoordsE coords_e(float px, float py, float pz) {
    float gx = fminf(fmaxf((px + 1.0f) * 79.5f, 0.0f), 159.0f);
    float gy = fminf(fmaxf((py + 1.0f) * 79.5f, 0.0f), 159.0f);
    float gz = fminf(fmaxf((pz + 1.0f) * 79.5f, 0.0f), 159.0f);
    int ix = (int)gx; if (ix > 158) ix = 158;
    int iy = (int)gy; if (iy > 158) iy = 158;
    int iz = (int)gz; if (iz > 158) iz = 158;
    int ze = iz & ~1; if (ze > 156) ze = 156;
    CoordsE c;
    c.base = (ix * G + iy) * G + ze;
    c.d = iz - ze;
    c.fx = gx - (float)ix; c.fy = gy - (float)iy; c.fz = gz - (float)iz;
    return c;
}

// mode: 0 = buffers hold bf16, 1 = buffers hold fp32
__global__ void decide_mode(const u16* __restrict__ rays_d_u16, int* __restrict__ mode) {
    if (blockIdx.x == 0 && threadIdx.x == 0) {
        int bad = 0;
        for (int i = 0; i < 128; i++) {
            u16 u = rays_d_u16[i];
            int e = (u >> 7) & 0xFF;
            int m = u & 0x7F;
            float v = bf2f(u);
            if (e == 0xFF || (e == 0 && m != 0) || fabsf(v) > 32.0f) bad++;
        }
        *mode = (bad >= 4) ? 1 : 0;
    }
}

// pre-pack W1 (frag-swizzled) and W0T (zero-padded K=16) into workspace, bf16.
// One-time: every dvgo block used to re-stage these 36 KB into LDS.
__global__ void pack_weights(const void* __restrict__ W1, const void* __restrict__ W0,
                             u16* __restrict__ w1g, u16* __restrict__ w0g,
                             const int* __restrict__ mode) {
    const int m = *mode;
    const int idx = blockIdx.x * 256 + threadIdx.x;
    for (int i = idx; i < WIDTH * WIDTH; i += 64 * 256) {
        int k = i >> 7, n = i & 127;
        float v = m ? ((const float*)W1)[i] : bf2f(((const u16*)W1)[i]);
        w1g[W1F_IDX(k >> 5, (k >> 3) & 3, n) + (k & 7)] = f2bf(v);
    }
    for (int i = idx; i < WIDTH * 16; i += 64 * 256) {
        int n = i >> 4, k = i & 15;
        float v = 0.0f;
        if (k < K0DIM) v = m ? ((const float*)W0)[k * WIDTH + n] : bf2f(((const u16*)W0)[k * WIDTH + n]);
        w0g[i] = f2bf(v);
    }
}

template <typename T, typename OT, int MODE>
__global__ __launch_bounds__(256, 6)
void dvgo_fused(const T* __restrict__ rays_o, const T* __restrict__ rays_d,
                const T* __restrict__ density, const T* __restrict__ k0,
                const T* __restrict__ W0, const T* __restrict__ b0,
                const T* __restrict__ W1, const T* __restrict__ b1,
                const T* __restrict__ W2, const T* __restrict__ b2,
                const u16* __restrict__ w1g, const u16* __restrict__ w0g,
                OT* __restrict__ out, const int* __restrict__ mode)
{
    if (*mode != MODE) return;   // uniform early-exit for the wrong-dtype instantiation

    using qvec = typename QT<T>::type;

    __shared__ __align__(16) u16   h0B[CHUNK * HBS];       // 8704 B   h0 bf16 [sample][k]
    __shared__ __align__(16) u16   featB[CHUNK * 16];      // 1024 B   feat bf16 [sample][k<=15]
    __shared__ __align__(16) float W2Tf[3 * WIDTH];        // 1536 B
    __shared__ float p2[CHUNK * 6];                        // 768 B  [s][nh][c]
    __shared__ float base0[WIDTH];
    __shared__ float b1s[WIDTH];
    __shared__ float b2s[3];
    __shared__ float vembs[27];
    __shared__ float wts[NS];
    __shared__ float red[96];
    __shared__ float ainvs;

    const int r = blockIdx.x;
    const int tid = threadIdx.x;

    const float o0 = loadv(rays_o, r*3+0);
    const float o1 = loadv(rays_o, r*3+1);
    const float o2 = loadv(rays_o, r*3+2);
    const float d0 = loadv(rays_d, r*3+0);
    const float d1 = loadv(rays_d, r*3+1);
    const float d2 = loadv(rays_d, r*3+2);

    // ---- stage small per-block tables into LDS ----
    for (int i = tid; i < CHUNK*4; i += 256)          // featB k=12..15 stays 0 forever
        featB[(i >> 2)*16 + 12 + (i & 3)] = 0;
    for (int k = tid; k < 3*WIDTH; k += 256) {
        int c = k >> 7, i = k & 127;
        W2Tf[k] = loadv(W2, i*3 + c);
    }
    if (tid < WIDTH) b1s[tid] = loadv(b1, tid);
    if (tid < 3)     b2s[tid] = loadv(b2, tid);

    // ---- view embedding (per-ray constant) ----
    if (tid < 27) {
        float inv = rsqrtf(d0*d0 + d1*d1 + d2*d2);
        float v0 = d0*inv, v1 = d1*inv, v2 = d2*inv;
        float val;
        if (tid < 3) {
            val = (tid == 0) ? v0 : ((tid == 1) ? v1 : v2);
        } else if (tid < 15) {
            int t2 = tid - 3; int dd = t2 >> 2; int p = t2 & 3;
            float vd = (dd == 0) ? v0 : ((dd == 1) ? v1 : v2);
            val = sinf(vd * (float)(1 << p));
        } else {
            int t2 = tid - 15; int dd = t2 >> 2; int p = t2 & 3;
            float vd = (dd == 0) ? v0 : ((dd == 1) ? v1 : v2);
            val = cosf(vd * (float)(1 << p));
        }
        vembs[tid] = val;
    }
    __syncthreads();

    // ---- base0 = b0 + vemb @ W0[12:39]  (per-ray) ----
    if (tid < WIDTH) {
        float a = loadv(b0, tid);
        #pragma unroll
        for (int i = 0; i < 27; i++)
            a += vembs[i] * loadv(W0, (K0DIM + i)*WIDTH + tid);
        base0[tid] = a;
    }

    // ---- alpha for my sample (quad-load gather) ----
    {
        int s = tid;
        float tv = TNEAR + (TFAR - TNEAR) * ((float)s * (1.0f/(float)(NS-1)));
        CoordsE c = coords_e(o0 + d0*tv, o1 + d1*tv, o2 + d2*tv);
        qvec q00 = *(const qvec*)(density + c.base);
        qvec q01 = *(const qvec*)(density + c.base + G);
        qvec q10 = *(const qvec*)(density + c.base + G2);
        qvec q11 = *(const qvec*)(density + c.base + G2 + G);
        float a0,a1,b0v,b1v,c0v,c1v,d0v,d1v;
        zpair(q00, c.d, a0, a1); zpair(q01, c.d, b0v, b1v);
        zpair(q10, c.d, c0v, c1v); zpair(q11, c.d, d0v, d1v);
        float c00 = a0*(1.0f-c.fz) + a1*c.fz;
        float c01 = b0v*(1.0f-c.fz) + b1v*c.fz;
        float c10 = c0v*(1.0f-c.fz) + c1v*c.fz;
        float c11 = d0v*(1.0f-c.fz) + d1v*c.fz;
        float e0 = c00*(1.0f-c.fy) + c01*c.fy;
        float e1 = c10*(1.0f-c.fy) + c11*c.fy;
        float sigma = e0*(1.0f-c.fx) + e1*c.fx;
        float alpha = 1.0f - rsqrtf(1.0f + __expf(sigma + ACT_SHIFT_F));
        wts[s] = alpha;
    }
    __syncthreads();

    // ---- wave-parallel transmittance scan (was: 256 serial iterations on tid 0) ----
    if (tid < 64) {
        const int l = tid;
        float a0 = wts[4*l+0], a1 = wts[4*l+1], a2 = wts[4*l+2], a3 = wts[4*l+3];
        float m0 = 1.0f - a0 + 1e-10f;
        float m1 = 1.0f - a1 + 1e-10f;
        float m2 = 1.0f - a2 + 1e-10f;
        float m3 = 1.0f - a3 + 1e-10f;
        float sc = (m0*m1)*(m2*m3);
        #pragma unroll
        for (int dlt = 1; dlt < 64; dlt <<= 1) {
            float o = __shfl_up(sc, dlt, 64);
            if (l >= dlt) sc *= o;
        }
        float Tr = __shfl_up(sc, 1, 64);
        if (l == 0) Tr = 1.0f;
        wts[4*l+0] = a0 * Tr; Tr *= m0;
        wts[4*l+1] = a1 * Tr; Tr *= m1;
        wts[4*l+2] = a2 * Tr; Tr *= m2;
        wts[4*l+3] = a3 * Tr; Tr *= m3;
        if (l == 63) ainvs = Tr;
    }
    __syncthreads();

    // ---- per-thread role constants ----
    const int lane = tid & 63;
    const int wvid = tid >> 6;
    const int mt   = wvid & 1;
    const int nh   = wvid >> 1;
    const int q    = lane >> 4;
    const int ncol = lane & 15;
    const int arow = mt*16 + ncol;
    const int kcol = q * 8;
    const int drow0 = mt*16 + q*4;

    // gather-prefetch state (2 tasks: tid and tid+256 if < 384)
    qvec qa[4], qb[4];
    CoordsE cea, ceb;
    const int ch0 = tid >> 5;              // task 0 channel (0..7)
    const int sl0 = tid & 31;
    const int ch1 = 8 + (tid >> 5);        // task 1 channel (8..11) for tid<128
    const int sl1 = tid & 31;
    const bool has1 = (tid < 128);
    const u32 chb0 = (u32)ch0 * (u32)G3;   // 32-bit element offsets (k0 = 49.2M elems max)
    const u32 chb1 = (u32)ch1 * (u32)G3;

    #define ISSUE_GATHER(CHB, SL, C0N, Q, CE)                                   \
        { int s_ = (C0N) + (SL);                                                \
          float tv_ = TNEAR + (TFAR - TNEAR) * ((float)s_ * (1.0f/255.0f));     \
          CE = coords_e(o0 + d0*tv_, o1 + d1*tv_, o2 + d2*tv_);                 \
          const T* g_ = k0 + ((CHB) + (u32)CE.base);                            \
          Q[0] = *(const qvec*)(g_);                                            \
          Q[1] = *(const qvec*)(g_ + G);                                        \
          Q[2] = *(const qvec*)(g_ + G2);                                       \
          Q[3] = *(const qvec*)(g_ + G2 + G); }

    #define COMMIT_GATHER(CH, SL, Q, CE)                                        \
        { float a0_,a1_,b0_,b1_,c0_,c1_,d0_,d1_;                                \
          zpair(Q[0], CE.d, a0_, a1_); zpair(Q[1], CE.d, b0_, b1_);             \
          zpair(Q[2], CE.d, c0_, c1_); zpair(Q[3], CE.d, d0_, d1_);             \
          float fz_ = CE.fz, fy_ = CE.fy, fx_ = CE.fx;                          \
          float c00_ = a0_*(1.0f-fz_) + a1_*fz_;                                \
          float c01_ = b0_*(1.0f-fz_) + b1_*fz_;                                \
          float c10_ = c0_*(1.0f-fz_) + c1_*fz_;                                \
          float c11_ = d0_*(1.0f-fz_) + d1_*fz_;                                \
          float e0_ = c00_*(1.0f-fy_) + c01_*fy_;                               \
          float e1_ = c10_*(1.0f-fy_) + c11_*fy_;                               \
          featB[(SL)*16 + (CH)] = f2bf(e0_*(1.0f-fx_) + e1_*fx_); }

    // prologue: gather chunk 0
    ISSUE_GATHER(chb0, sl0, 0, qa, cea);
    if (has1) ISSUE_GATHER(chb1, sl1, 0, qb, ceb);

    float rgbacc = 0.0f;

    for (int cc = 0; cc < NCHUNK; cc++) {
        const int c0 = cc * CHUNK;

        // (a) commit gathered corners -> featB (bf16)
        COMMIT_GATHER(ch0, sl0, qa, cea);
        if (has1) COMMIT_GATHER(ch1, sl1, qb, ceb);
        __syncthreads();   // A: featB ready

        // (b) layer 0 via MFMA (K=12 zero-padded to 32):
        //     h0[32][128] = relu(base0 + feat[32][12] @ W0[12][128])
        {
            short8 af0 = {};
            short8 bf0 = {}, bf1 = {}, bf2v = {}, bf3 = {};
            if (q < 2) {
                af0  = *(const short8*)&featB[arow*16 + kcol];
                const u16* wp = w0g + ((nh*64 + ncol) << 4) + kcol;   // L2-hot, coalesced 16B
                bf0  = *(const short8*)(wp);
                bf1  = *(const short8*)(wp + (16 << 4));
                bf2v = *(const short8*)(wp + (32 << 4));
                bf3  = *(const short8*)(wp + (48 << 4));
            }
            floatx4 acc0[4];
            #pragma unroll
            for (int t = 0; t < 4; t++) {
                float v = base0[nh*64 + t*16 + ncol];
                acc0[t] = (floatx4){v, v, v, v};
            }
            acc0[0] = __builtin_amdgcn_mfma_f32_16x16x32_bf16(af0, bf0,  acc0[0], 0, 0, 0);
            acc0[1] = __builtin_amdgcn_mfma_f32_16x16x32_bf16(af0, bf1,  acc0[1], 0, 0, 0);
            acc0[2] = __builtin_amdgcn_mfma_f32_16x16x32_bf16(af0, bf2v, acc0[2], 0, 0, 0);
            acc0[3] = __builtin_amdgcn_mfma_f32_16x16x32_bf16(af0, bf3,  acc0[3], 0, 0, 0);
            // epilogue: ReLU -> bf16 -> h0B[sample][k] (A-layout for layer 1)
            #pragma unroll
            for (int t = 0; t < 4; t++) {
                int j = nh*64 + t*16 + ncol;
                #pragma unroll
                for (int rI = 0; rI < 4; rI++)
                    h0B[(drow0 + rI)*HBS + j] = f2bf(fmaxf(acc0[t][rI], 0.0f));
            }
        }
        __syncthreads();   // B: h0B ready

        // (c) issue next chunk's gathers (overlaps MFMA), then MFMA layer 1 + fused layer 2
        if (cc + 1 < NCHUNK) {
            ISSUE_GATHER(chb0, sl0, c0 + CHUNK, qa, cea);
            if (has1) ISSUE_GATHER(chb1, sl1, c0 + CHUNK, qb, ceb);
        }

        {
            floatx4 acc[4];
            #pragma unroll
            for (int t = 0; t < 4; t++) {
                float bj = b1s[nh*64 + t*16 + ncol];
                acc[t] = (floatx4){bj, bj, bj, bj};
            }
            // B-frags straight from the L2-resident pre-packed table (was LDS W1f)
            const u16* w1p = w1g + ((q*128 + nh*64 + ncol) << 3);
            #pragma unroll
            for (int kq = 0; kq < 4; kq++) {
                short8 af = *(const short8*)&h0B[arow*HBS + kq*32 + kcol];
                const u16* wk = w1p + (kq << 12);
                #pragma unroll
                for (int t = 0; t < 4; t++) {
                    short8 bf = *(const short8*)(wk + (t << 7));
                    acc[t] = __builtin_amdgcn_mfma_f32_16x16x32_bf16(af, bf, acc[t], 0, 0, 0);
                }
            }

            // fused layer 2: per-lane partials over the 4 cols this lane owns
            float p[3][4];
            #pragma unroll
            for (int c = 0; c < 3; c++)
                { p[c][0]=0; p[c][1]=0; p[c][2]=0; p[c][3]=0; }
            #pragma unroll
            for (int t = 0; t < 4; t++) {
                int j = nh*64 + t*16 + ncol;
                float w20 = W2Tf[j], w21 = W2Tf[WIDTH + j], w22 = W2Tf[2*WIDTH + j];
                #pragma unroll
                for (int rI = 0; rI < 4; rI++) {
                    float h = fmaxf(acc[t][rI], 0.0f);
                    p[0][rI] += h * w20;
                    p[1][rI] += h * w21;
                    p[2][rI] += h * w22;
                }
            }
            // reduce over the 16 ncol lanes (bits 0..3 of lane)
            #pragma unroll
            for (int m = 1; m <= 8; m <<= 1) {
                #pragma unroll
                for (int c = 0; c < 3; c++) {
                    #pragma unroll
                    for (int rI = 0; rI < 4; rI++)
                        p[c][rI] += __shfl_xor(p[c][rI], m, 64);
                }
            }
            if (ncol == 0) {
                #pragma unroll
                for (int rI = 0; rI < 4; rI++) {
                    #pragma unroll
                    for (int c = 0; c < 3; c++)
                        p2[(drow0 + rI)*6 + nh*3 + c] = p[c][rI];
                }
            }
        }
        __syncthreads();   // C: p2 ready (also h0B consumed before next (b))

        // (d) sigmoid + weighted accumulate (96 threads)
        if (tid < 96) {
            int c = tid >> 5, s = tid & 31;
            float acc2 = b2s[c] + p2[s*6 + c] + p2[s*6 + 3 + c];
            float rgb = 1.0f / (1.0f + __expf(-acc2));
            rgbacc += wts[c0 + s] * rgb;
        }
        // no barrier needed: next p2 write is after next barriers A and B
    }

    if (tid < 96) red[tid] = rgbacc;
    __syncthreads();
    if (tid < 3) {
        float s = 0.0f;
        #pragma unroll
        for (int k = 0; k < 32; k++) s += red[tid*32 + k];
        storev(out, r*3 + tid, s + ainvs);
    }
    #undef ISSUE_GATHER
    #undef COMMIT_GATHER
}

extern "C" void kernel_launch(void* const* d_in, const int* in_sizes, int n_in,
                              void* d_out, int out_size, void* d_ws, size_t ws_size,
                              hipStream_t stream) {
    int* mode = (int*)d_ws;
    u16* w1g = (u16*)((char*)d_ws + WS_W1G_OFF);
    u16* w0g = (u16*)((char*)d_ws + WS_W0G_OFF);

    decide_mode<<<dim3(1), dim3(64), 0, stream>>>((const u16*)d_in[1], mode);
    pack_weights<<<dim3(64), dim3(256), 0, stream>>>(d_in[6], d_in[4], w1g, w0g, mode);

    // bf16 interpretation
    dvgo_fused<u16, u16, 0><<<dim3(NRAYS), dim3(256), 0, stream>>>(
        (const u16*)d_in[0], (const u16*)d_in[1], (const u16*)d_in[2],
        (const u16*)d_in[3], (const u16*)d_in[4], (const u16*)d_in[5],
        (const u16*)d_in[6], (const u16*)d_in[7], (const u16*)d_in[8],
        (const u16*)d_in[9], w1g, w0g, (u16*)d_out, mode);

    // fp32 interpretation
    dvgo_fused<float, float, 1><<<dim3(NRAYS), dim3(256), 0, stream>>>(
        (const float*)d_in[0], (const float*)d_in[1], (const float*)d_in[2],
        (const float*)d_in[3], (const float*)d_in[4], (const float*)d_in[5],
        (const float*)d_in[6], (const float*)d_in[7], (const float*)d_in[8],
        (const float*)d_in[9], w1g, w0g, (float*)d_out, mode);
}

// Round 2
// 784.972 us; speedup vs baseline: 1.9638x; 1.9638x over previous
//
#include <hip/hip_runtime.h>
#include <hip/hip_bf16.h>

#define NRAYS 4096
#define NS 256
#define G 160
#define G2 (160*160)
#define G3 (160*160*160)
#define K0DIM 12
#define WIDTH 128
#define CHUNK 32
#define NCHUNK 8
#define HBS 136              // h0B bf16 row stride (272 B: 16B-aligned rows, 2-way banks = free)
#define ACT_SHIFT_F (-4.5951198501345889f)
#define TNEAR 0.2f
#define TFAR 1.8f

// workspace layout: [0] mode (int); +1024: W1G frag table (32768 B); +33792: W0G (4096 B)
#define WS_W1G_OFF 1024
#define WS_W0G_OFF (1024 + 32768)

typedef unsigned short u16;
typedef unsigned int u32;
typedef __attribute__((ext_vector_type(8))) short short8;   // 8 bf16 = 4 VGPRs (MFMA A/B frag)
typedef __attribute__((ext_vector_type(4))) float floatx4;  // MFMA C/D frag

// W1G[kq][qsub][col][j]: B-frag for (kq, quarter qsub, output col) = 16 contiguous bytes
#define W1F_IDX(kq, qs, n) (((((kq)<<2) + (qs)) * 128 + (n)) << 3)

__device__ __forceinline__ float bf2f(u16 u) {
    union { u32 i; float f; } v; v.i = ((u32)u) << 16; return v.f;
}
__device__ __forceinline__ u16 f2bf(float f) {   // RTNE fp32 -> bf16
    union { float f; u32 u; } v; v.f = f;
    u32 r = v.u + 0x7FFFu + ((v.u >> 16) & 1u);
    return (u16)(r >> 16);
}

__device__ __forceinline__ float loadv(const float* p, int i) { return p[i]; }
__device__ __forceinline__ float loadv(const u16* p, int i)   { return bf2f(p[i]); }
__device__ __forceinline__ void storev(float* p, int i, float v) { p[i] = v; }
__device__ __forceinline__ void storev(u16* p, int i, float v)   { p[i] = f2bf(v); }

// z-quad raw vector type per dtype
template <typename T> struct QT;
template <> struct QT<u16>   { using type = ushort4; };
template <> struct QT<float> { using type = float4;  };

// select values at (z0, z0+1) = quad[d], quad[d+1], d in {0,1,2}
__device__ __forceinline__ void zpair(const ushort4& q, int d, float& v0, float& v1) {
    u16 r0 = (d == 0) ? q.x : ((d == 1) ? q.y : q.z);
    u16 r1 = (d == 0) ? q.y : ((d == 1) ? q.z : q.w);
    v0 = bf2f(r0); v1 = bf2f(r1);
}
__device__ __forceinline__ void zpair(const float4& q, int d, float& v0, float& v1) {
    v0 = (d == 0) ? q.x : ((d == 1) ? q.y : q.z);
    v1 = (d == 0) ? q.y : ((d == 1) ? q.z : q.w);
}

struct CoordsE { int base; int d; float fx, fy, fz; };

__device__ __forceinline__ CoordsE coords_e(float px, float py, float pz) {
    float gx = fminf(fmaxf((px + 1.0f) * 79.5f, 0.0f), 159.0f);
    float gy = fminf(fmaxf((py + 1.0f) * 79.5f, 0.0f), 159.0f);
    float gz = fminf(fmaxf((pz + 1.0f) * 79.5f, 0.0f), 159.0f);
    int ix = (int)gx; if (ix > 158) ix = 158;
    int iy = (int)gy; if (iy > 158) iy = 158;
    int iz = (int)gz; if (iz > 158) iz = 158;
    int ze = iz & ~1; if (ze > 156) ze = 156;
    CoordsE c;
    c.base = (ix * G + iy) * G + ze;
    c.d = iz - ze;
    c.fx = gx - (float)ix; c.fy = gy - (float)iy; c.fz = gz - (float)iz;
    return c;
}

// mode: 0 = buffers hold bf16, 1 = buffers hold fp32
__global__ void decide_mode(const u16* __restrict__ rays_d_u16, int* __restrict__ mode) {
    if (blockIdx.x == 0 && threadIdx.x == 0) {
        int bad = 0;
        for (int i = 0; i < 128; i++) {
            u16 u = rays_d_u16[i];
            int e = (u >> 7) & 0xFF;
            int m = u & 0x7F;
            float v = bf2f(u);
            if (e == 0xFF || (e == 0 && m != 0) || fabsf(v) > 32.0f) bad++;
        }
        *mode = (bad >= 4) ? 1 : 0;
    }
}

// pre-pack W1 (frag-swizzled) and W0T (zero-padded K=16) into workspace, bf16.
__global__ void pack_weights(const void* __restrict__ W1, const void* __restrict__ W0,
                             u16* __restrict__ w1g, u16* __restrict__ w0g,
                             const int* __restrict__ mode) {
    const int m = *mode;
    const int idx = blockIdx.x * 256 + threadIdx.x;
    for (int i = idx; i < WIDTH * WIDTH; i += 64 * 256) {
        int k = i >> 7, n = i & 127;
        float v = m ? ((const float*)W1)[i] : bf2f(((const u16*)W1)[i]);
        w1g[W1F_IDX(k >> 5, (k >> 3) & 3, n) + (k & 7)] = f2bf(v);
    }
    for (int i = idx; i < WIDTH * 16; i += 64 * 256) {
        int n = i >> 4, k = i & 15;
        float v = 0.0f;
        if (k < K0DIM) v = m ? ((const float*)W0)[k * WIDTH + n] : bf2f(((const u16*)W0)[k * WIDTH + n]);
        w0g[i] = f2bf(v);
    }
}

template <typename T, typename OT, int MODE>
__global__ __launch_bounds__(256, 4)      // VGPR cap 128: rnd1's cap-85 forced scratch spills (2.2 GB writes)
void dvgo_fused(const T* __restrict__ rays_o, const T* __restrict__ rays_d,
                const T* __restrict__ density, const T* __restrict__ k0,
                const T* __restrict__ W0, const T* __restrict__ b0,
                const T* __restrict__ W1, const T* __restrict__ b1,
                const T* __restrict__ W2, const T* __restrict__ b2,
                const u16* __restrict__ w1g, const u16* __restrict__ w0g,
                OT* __restrict__ out, const int* __restrict__ mode)
{
    if (*mode != MODE) return;   // uniform early-exit for the wrong-dtype instantiation

    using qvec = typename QT<T>::type;

    __shared__ __align__(16) u16   h0B[CHUNK * HBS];       // 8704 B   h0 bf16 [sample][k]
    __shared__ __align__(16) u16   featB[CHUNK * 16];      // 1024 B   feat bf16 [sample][k<=15]
    __shared__ __align__(16) float W2Tf[3 * WIDTH];        // 1536 B
    __shared__ float p2[CHUNK * 6];                        // 768 B  [s][nh][c]
    __shared__ float base0[WIDTH];
    __shared__ float b1s[WIDTH];
    __shared__ float b2s[3];
    __shared__ float vembs[27];
    __shared__ float wts[NS];
    __shared__ float red[96];
    __shared__ float ainvs;

    const int r = blockIdx.x;
    const int tid = threadIdx.x;

    const float o0 = loadv(rays_o, r*3+0);
    const float o1 = loadv(rays_o, r*3+1);
    const float o2 = loadv(rays_o, r*3+2);
    const float d0 = loadv(rays_d, r*3+0);
    const float d1 = loadv(rays_d, r*3+1);
    const float d2 = loadv(rays_d, r*3+2);

    // ---- stage small per-block tables into LDS ----
    for (int i = tid; i < CHUNK*4; i += 256)          // featB k=12..15 stays 0 forever
        featB[(i >> 2)*16 + 12 + (i & 3)] = 0;
    for (int k = tid; k < 3*WIDTH; k += 256) {
        int c = k >> 7, i = k & 127;
        W2Tf[k] = loadv(W2, i*3 + c);
    }
    if (tid < WIDTH) b1s[tid] = loadv(b1, tid);
    if (tid < 3)     b2s[tid] = loadv(b2, tid);

    // ---- view embedding (per-ray constant) ----
    if (tid < 27) {
        float inv = rsqrtf(d0*d0 + d1*d1 + d2*d2);
        float v0 = d0*inv, v1 = d1*inv, v2 = d2*inv;
        float val;
        if (tid < 3) {
            val = (tid == 0) ? v0 : ((tid == 1) ? v1 : v2);
        } else if (tid < 15) {
            int t2 = tid - 3; int dd = t2 >> 2; int p = t2 & 3;
            float vd = (dd == 0) ? v0 : ((dd == 1) ? v1 : v2);
            val = sinf(vd * (float)(1 << p));
        } else {
            int t2 = tid - 15; int dd = t2 >> 2; int p = t2 & 3;
            float vd = (dd == 0) ? v0 : ((dd == 1) ? v1 : v2);
            val = cosf(vd * (float)(1 << p));
        }
        vembs[tid] = val;
    }
    __syncthreads();

    // ---- base0 = b0 + vemb @ W0[12:39]  (per-ray) ----
    if (tid < WIDTH) {
        float a = loadv(b0, tid);
        #pragma unroll
        for (int i = 0; i < 27; i++)
            a += vembs[i] * loadv(W0, (K0DIM + i)*WIDTH + tid);
        base0[tid] = a;
    }

    // ---- alpha for my sample (quad-load gather) ----
    {
        int s = tid;
        float tv = TNEAR + (TFAR - TNEAR) * ((float)s * (1.0f/(float)(NS-1)));
        CoordsE c = coords_e(o0 + d0*tv, o1 + d1*tv, o2 + d2*tv);
        qvec q00 = *(const qvec*)(density + c.base);
        qvec q01 = *(const qvec*)(density + c.base + G);
        qvec q10 = *(const qvec*)(density + c.base + G2);
        qvec q11 = *(const qvec*)(density + c.base + G2 + G);
        float a0,a1,b0v,b1v,c0v,c1v,d0v,d1v;
        zpair(q00, c.d, a0, a1); zpair(q01, c.d, b0v, b1v);
        zpair(q10, c.d, c0v, c1v); zpair(q11, c.d, d0v, d1v);
        float c00 = a0*(1.0f-c.fz) + a1*c.fz;
        float c01 = b0v*(1.0f-c.fz) + b1v*c.fz;
        float c10 = c0v*(1.0f-c.fz) + c1v*c.fz;
        float c11 = d0v*(1.0f-c.fz) + d1v*c.fz;
        float e0 = c00*(1.0f-c.fy) + c01*c.fy;
        float e1 = c10*(1.0f-c.fy) + c11*c.fy;
        float sigma = e0*(1.0f-c.fx) + e1*c.fx;
        float alpha = 1.0f - rsqrtf(1.0f + __expf(sigma + ACT_SHIFT_F));
        wts[s] = alpha;
    }
    __syncthreads();

    // ---- wave-parallel transmittance scan ----
    if (tid < 64) {
        const int l = tid;
        float a0 = wts[4*l+0], a1 = wts[4*l+1], a2 = wts[4*l+2], a3 = wts[4*l+3];
        float m0 = 1.0f - a0 + 1e-10f;
        float m1 = 1.0f - a1 + 1e-10f;
        float m2 = 1.0f - a2 + 1e-10f;
        float m3 = 1.0f - a3 + 1e-10f;
        float sc = (m0*m1)*(m2*m3);
        #pragma unroll
        for (int dlt = 1; dlt < 64; dlt <<= 1) {
            float o = __shfl_up(sc, dlt, 64);
            if (l >= dlt) sc *= o;
        }
        float Tr = __shfl_up(sc, 1, 64);
        if (l == 0) Tr = 1.0f;
        wts[4*l+0] = a0 * Tr; Tr *= m0;
        wts[4*l+1] = a1 * Tr; Tr *= m1;
        wts[4*l+2] = a2 * Tr; Tr *= m2;
        wts[4*l+3] = a3 * Tr; Tr *= m3;
        if (l == 63) ainvs = Tr;
    }
    __syncthreads();

    // ---- per-thread role constants ----
    const int lane = tid & 63;
    const int wvid = tid >> 6;
    const int mt   = wvid & 1;
    const int nh   = wvid >> 1;
    const int q    = lane >> 4;
    const int ncol = lane & 15;
    const int arow = mt*16 + ncol;
    const int kcol = q * 8;
    const int drow0 = mt*16 + q*4;

    // gather-prefetch state (2 tasks: tid and tid+256 if < 384)
    qvec qa[4], qb[4];
    CoordsE cea, ceb;
    const int ch0 = tid >> 5;              // task 0 channel (0..7)
    const int sl0 = tid & 31;
    const int ch1 = 8 + (tid >> 5);        // task 1 channel (8..11) for tid<128
    const int sl1 = tid & 31;
    const bool has1 = (tid < 128);
    const u32 chb0 = (u32)ch0 * (u32)G3;   // 32-bit element offsets
    const u32 chb1 = (u32)ch1 * (u32)G3;

    #define ISSUE_GATHER(CHB, SL, C0N, Q, CE)                                   \
        { int s_ = (C0N) + (SL);                                                \
          float tv_ = TNEAR + (TFAR - TNEAR) * ((float)s_ * (1.0f/255.0f));     \
          CE = coords_e(o0 + d0*tv_, o1 + d1*tv_, o2 + d2*tv_);                 \
          const T* g_ = k0 + ((CHB) + (u32)CE.base);                            \
          Q[0] = *(const qvec*)(g_);                                            \
          Q[1] = *(const qvec*)(g_ + G);                                        \
          Q[2] = *(const qvec*)(g_ + G2);                                       \
          Q[3] = *(const qvec*)(g_ + G2 + G); }

    #define COMMIT_GATHER(CH, SL, Q, CE)                                        \
        { float a0_,a1_,b0_,b1_,c0_,c1_,d0_,d1_;                                \
          zpair(Q[0], CE.d, a0_, a1_); zpair(Q[1], CE.d, b0_, b1_);             \
          zpair(Q[2], CE.d, c0_, c1_); zpair(Q[3], CE.d, d0_, d1_);             \
          float fz_ = CE.fz, fy_ = CE.fy, fx_ = CE.fx;                          \
          float c00_ = a0_*(1.0f-fz_) + a1_*fz_;                                \
          float c01_ = b0_*(1.0f-fz_) + b1_*fz_;                                \
          float c10_ = c0_*(1.0f-fz_) + c1_*fz_;                                \
          float c11_ = d0_*(1.0f-fz_) + d1_*fz_;                                \
          float e0_ = c00_*(1.0f-fy_) + c01_*fy_;                               \
          float e1_ = c10_*(1.0f-fy_) + c11_*fy_;                               \
          featB[(SL)*16 + (CH)] = f2bf(e0_*(1.0f-fx_) + e1_*fx_); }

    // prologue: gather chunk 0
    ISSUE_GATHER(chb0, sl0, 0, qa, cea);
    if (has1) ISSUE_GATHER(chb1, sl1, 0, qb, ceb);

    float rgbacc = 0.0f;

    for (int cc = 0; cc < NCHUNK; cc++) {
        const int c0 = cc * CHUNK;

        // (a) commit gathered corners -> featB (bf16)
        COMMIT_GATHER(ch0, sl0, qa, cea);
        if (has1) COMMIT_GATHER(ch1, sl1, qb, ceb);
        __syncthreads();   // A: featB ready

        // (b) layer 0 via MFMA (K=12 zero-padded to 32):
        //     h0[32][128] = relu(base0 + feat[32][12] @ W0[12][128])
        {
            short8 af0 = {};
            short8 bf0 = {}, bf1 = {}, bf2v = {}, bf3 = {};
            if (q < 2) {
                af0  = *(const short8*)&featB[arow*16 + kcol];
                const u16* wp = w0g + ((nh*64 + ncol) << 4) + kcol;   // L2-hot, coalesced 16B
                bf0  = *(const short8*)(wp);
                bf1  = *(const short8*)(wp + (16 << 4));
                bf2v = *(const short8*)(wp + (32 << 4));
                bf3  = *(const short8*)(wp + (48 << 4));
            }
            floatx4 acc0[4];
            #pragma unroll
            for (int t = 0; t < 4; t++) {
                float v = base0[nh*64 + t*16 + ncol];
                acc0[t] = (floatx4){v, v, v, v};
            }
            acc0[0] = __builtin_amdgcn_mfma_f32_16x16x32_bf16(af0, bf0,  acc0[0], 0, 0, 0);
            acc0[1] = __builtin_amdgcn_mfma_f32_16x16x32_bf16(af0, bf1,  acc0[1], 0, 0, 0);
            acc0[2] = __builtin_amdgcn_mfma_f32_16x16x32_bf16(af0, bf2v, acc0[2], 0, 0, 0);
            acc0[3] = __builtin_amdgcn_mfma_f32_16x16x32_bf16(af0, bf3,  acc0[3], 0, 0, 0);
            // epilogue: ReLU -> bf16 -> h0B[sample][k] (A-layout for layer 1)
            #pragma unroll
            for (int t = 0; t < 4; t++) {
                int j = nh*64 + t*16 + ncol;
                #pragma unroll
                for (int rI = 0; rI < 4; rI++)
                    h0B[(drow0 + rI)*HBS + j] = f2bf(fmaxf(acc0[t][rI], 0.0f));
            }
        }
        __syncthreads();   // B: h0B ready

        // (c) issue next chunk's gathers (overlaps MFMA), then MFMA layer 1 + fused layer 2
        if (cc + 1 < NCHUNK) {
            ISSUE_GATHER(chb0, sl0, c0 + CHUNK, qa, cea);
            if (has1) ISSUE_GATHER(chb1, sl1, c0 + CHUNK, qb, ceb);
        }

        {
            floatx4 acc[4];
            #pragma unroll
            for (int t = 0; t < 4; t++) {
                float bj = b1s[nh*64 + t*16 + ncol];
                acc[t] = (floatx4){bj, bj, bj, bj};
            }
            // B-frags straight from the L2-resident pre-packed table (was LDS W1f)
            const u16* w1p = w1g + ((q*128 + nh*64 + ncol) << 3);
            #pragma unroll
            for (int kq = 0; kq < 4; kq++) {
                short8 af = *(const short8*)&h0B[arow*HBS + kq*32 + kcol];
                const u16* wk = w1p + (kq << 12);
                #pragma unroll
                for (int t = 0; t < 4; t++) {
                    short8 bf = *(const short8*)(wk + (t << 7));
                    acc[t] = __builtin_amdgcn_mfma_f32_16x16x32_bf16(af, bf, acc[t], 0, 0, 0);
                }
            }

            // fused layer 2: per-lane partials over the 4 cols this lane owns
            float p[3][4];
            #pragma unroll
            for (int c = 0; c < 3; c++)
                { p[c][0]=0; p[c][1]=0; p[c][2]=0; p[c][3]=0; }
            #pragma unroll
            for (int t = 0; t < 4; t++) {
                int j = nh*64 + t*16 + ncol;
                float w20 = W2Tf[j], w21 = W2Tf[WIDTH + j], w22 = W2Tf[2*WIDTH + j];
                #pragma unroll
                for (int rI = 0; rI < 4; rI++) {
                    float h = fmaxf(acc[t][rI], 0.0f);
                    p[0][rI] += h * w20;
                    p[1][rI] += h * w21;
                    p[2][rI] += h * w22;
                }
            }
            // reduce over the 16 ncol lanes (bits 0..3 of lane)
            #pragma unroll
            for (int m = 1; m <= 8; m <<= 1) {
                #pragma unroll
                for (int c = 0; c < 3; c++) {
                    #pragma unroll
                    for (int rI = 0; rI < 4; rI++)
                        p[c][rI] += __shfl_xor(p[c][rI], m, 64);
                }
            }
            if (ncol == 0) {
                #pragma unroll
                for (int rI = 0; rI < 4; rI++) {
                    #pragma unroll
                    for (int c = 0; c < 3; c++)
                        p2[(drow0 + rI)*6 + nh*3 + c] = p[c][rI];
                }
            }
        }
        __syncthreads();   // C: p2 ready (also h0B consumed before next (b))

        // (d) sigmoid + weighted accumulate (96 threads)
        if (tid < 96) {
            int c = tid >> 5, s = tid & 31;
            float acc2 = b2s[c] + p2[s*6 + c] + p2[s*6 + 3 + c];
            float rgb = 1.0f / (1.0f + __expf(-acc2));
            rgbacc += wts[c0 + s] * rgb;
        }
        // no barrier needed: next p2 write is after next barriers A and B
    }

    if (tid < 96) red[tid] = rgbacc;
    __syncthreads();
    if (tid < 3) {
        float s = 0.0f;
        #pragma unroll
        for (int k = 0; k < 32; k++) s += red[tid*32 + k];
        storev(out, r*3 + tid, s + ainvs);
    }
    #undef ISSUE_GATHER
    #undef COMMIT_GATHER
}

extern "C" void kernel_launch(void* const* d_in, const int* in_sizes, int n_in,
                              void* d_out, int out_size, void* d_ws, size_t ws_size,
                              hipStream_t stream) {
    int* mode = (int*)d_ws;
    u16* w1g = (u16*)((char*)d_ws + WS_W1G_OFF);
    u16* w0g = (u16*)((char*)d_ws + WS_W0G_OFF);

    decide_mode<<<dim3(1), dim3(64), 0, stream>>>((const u16*)d_in[1], mode);
    pack_weights<<<dim3(64), dim3(256), 0, stream>>>(d_in[6], d_in[4], w1g, w0g, mode);

    // bf16 interpretation
    dvgo_fused<u16, u16, 0><<<dim3(NRAYS), dim3(256), 0, stream>>>(
        (const u16*)d_in[0], (const u16*)d_in[1], (const u16*)d_in[2],
        (const u16*)d_in[3], (const u16*)d_in[4], (const u16*)d_in[5],
        (const u16*)d_in[6], (const u16*)d_in[7], (const u16*)d_in[8],
        (const u16*)d_in[9], w1g, w0g, (u16*)d_out, mode);

    // fp32 interpretation
    dvgo_fused<float, float, 1><<<dim3(NRAYS), dim3(256), 0, stream>>>(
        (const float*)d_in[0], (const float*)d_in[1], (const float*)d_in[2],
        (const float*)d_in[3], (const float*)d_in[4], (const float*)d_in[5],
        (const float*)d_in[6], (const float*)d_in[7], (const float*)d_in[8],
        (const float*)d_in[9], w1g, w0g, (float*)d_out, mode);
}

// Round 3
// 529.753 us; speedup vs baseline: 2.9099x; 1.4818x over previous
//
#include <hip/hip_runtime.h>
#include <hip/hip_bf16.h>

#define NRAYS 4096
#define NS 256
#define G 160
#define G2 (160*160)
#define G3 (160*160*160)
#define K0DIM 12
#define WIDTH 128
#define CHUNK 16
#define NCHUNK 16
#define HBS 136              // h0B bf16 row stride (272 B)
#define ACT_SHIFT_F (-4.5951198501345889f)
#define TNEAR 0.2f
#define TFAR 1.8f

// workspace layout: [0] mode (int); +1024: W1G frag table (32768 B); +33792: W0G (4096 B)
#define WS_W1G_OFF 1024
#define WS_W0G_OFF (1024 + 32768)

typedef unsigned short u16;
typedef unsigned int u32;
typedef __attribute__((ext_vector_type(8))) short short8;   // 8 bf16 = 4 VGPRs (MFMA A/B frag)
typedef __attribute__((ext_vector_type(4))) float floatx4;  // MFMA C/D frag

// W1G[kq][qsub][col][j]: B-frag for (kq, quarter qsub, output col) = 16 contiguous bytes
#define W1F_IDX(kq, qs, n) (((((kq)<<2) + (qs)) * 128 + (n)) << 3)

__device__ __forceinline__ float bf2f(u16 u) {
    union { u32 i; float f; } v; v.i = ((u32)u) << 16; return v.f;
}
__device__ __forceinline__ u16 f2bf(float f) {   // RTNE fp32 -> bf16
    union { float f; u32 u; } v; v.f = f;
    u32 r = v.u + 0x7FFFu + ((v.u >> 16) & 1u);
    return (u16)(r >> 16);
}

__device__ __forceinline__ float loadv(const float* p, int i) { return p[i]; }
__device__ __forceinline__ float loadv(const u16* p, int i)   { return bf2f(p[i]); }
__device__ __forceinline__ void storev(float* p, int i, float v) { p[i] = v; }
__device__ __forceinline__ void storev(u16* p, int i, float v)   { p[i] = f2bf(v); }
__device__ __forceinline__ float tofl(float v) { return v; }
__device__ __forceinline__ float tofl(u16 v)   { return bf2f(v); }

struct Coords { int base; float fx, fy, fz; };

__device__ __forceinline__ Coords coords_n(float px, float py, float pz) {
    float gx = fminf(fmaxf((px + 1.0f) * 79.5f, 0.0f), 159.0f);
    float gy = fminf(fmaxf((py + 1.0f) * 79.5f, 0.0f), 159.0f);
    float gz = fminf(fmaxf((pz + 1.0f) * 79.5f, 0.0f), 159.0f);
    int ix = (int)gx; if (ix > 158) ix = 158;
    int iy = (int)gy; if (iy > 158) iy = 158;
    int iz = (int)gz; if (iz > 158) iz = 158;
    Coords c;
    c.base = (ix * G + iy) * G + iz;
    c.fx = gx - (float)ix; c.fy = gy - (float)iy; c.fz = gz - (float)iz;
    return c;
}

// mode: 0 = buffers hold bf16, 1 = buffers hold fp32
__global__ void decide_mode(const u16* __restrict__ rays_d_u16, int* __restrict__ mode) {
    if (blockIdx.x == 0 && threadIdx.x == 0) {
        int bad = 0;
        for (int i = 0; i < 128; i++) {
            u16 u = rays_d_u16[i];
            int e = (u >> 7) & 0xFF;
            int m = u & 0x7F;
            float v = bf2f(u);
            if (e == 0xFF || (e == 0 && m != 0) || fabsf(v) > 32.0f) bad++;
        }
        *mode = (bad >= 4) ? 1 : 0;
    }
}

// pre-pack W1 (frag-swizzled) and W0T (zero-padded K=16) into workspace, bf16.
__global__ void pack_weights(const void* __restrict__ W1, const void* __restrict__ W0,
                             u16* __restrict__ w1g, u16* __restrict__ w0g,
                             const int* __restrict__ mode) {
    const int m = *mode;
    const int idx = blockIdx.x * 256 + threadIdx.x;
    for (int i = idx; i < WIDTH * WIDTH; i += 64 * 256) {
        int k = i >> 7, n = i & 127;
        float v = m ? ((const float*)W1)[i] : bf2f(((const u16*)W1)[i]);
        w1g[W1F_IDX(k >> 5, (k >> 3) & 3, n) + (k & 7)] = f2bf(v);
    }
    for (int i = idx; i < WIDTH * 16; i += 64 * 256) {
        int n = i >> 4, k = i & 15;
        float v = 0.0f;
        if (k < K0DIM) v = m ? ((const float*)W0)[k * WIDTH + n] : bf2f(((const u16*)W0)[k * WIDTH + n]);
        w0g[i] = f2bf(v);
    }
}

template <typename T, typename OT, int MODE>
__global__ __launch_bounds__(256, 4)      // cap 128 VGPR; W1 lives in 32 regs/thread
void dvgo_fused(const T* __restrict__ rays_o, const T* __restrict__ rays_d,
                const T* __restrict__ density, const T* __restrict__ k0,
                const T* __restrict__ W0, const T* __restrict__ b0,
                const T* __restrict__ W1, const T* __restrict__ b1,
                const T* __restrict__ W2, const T* __restrict__ b2,
                const u16* __restrict__ w1g, const u16* __restrict__ w0g,
                OT* __restrict__ out, const int* __restrict__ mode)
{
    if (*mode != MODE) return;   // uniform early-exit for the wrong-dtype instantiation

    __shared__ __align__(16) u16   h0B[CHUNK * HBS];       // 4352 B  h0 bf16 [sample][k]
    __shared__ __align__(16) u16   featB[CHUNK * 16];      // 512 B   feat bf16 [sample][k<=15]
    __shared__ __align__(16) float W2Tf[3 * WIDTH];        // 1536 B
    __shared__ float p2[CHUNK * 12];                       // 768 B   [s][wave][c]
    __shared__ float base0[WIDTH];
    __shared__ float b1s[WIDTH];
    __shared__ float b2s[3];
    __shared__ float vembs[27];
    __shared__ float wts[NS];
    __shared__ float red[48];
    __shared__ float ainvs;

    const int r = blockIdx.x;
    const int tid = threadIdx.x;

    const float o0 = loadv(rays_o, r*3+0);
    const float o1 = loadv(rays_o, r*3+1);
    const float o2 = loadv(rays_o, r*3+2);
    const float d0 = loadv(rays_d, r*3+0);
    const float d1 = loadv(rays_d, r*3+1);
    const float d2 = loadv(rays_d, r*3+2);

    // ---- per-thread role constants ----
    const int lane = tid & 63;
    const int wvid = tid >> 6;
    const int q    = lane >> 4;
    const int ncol = lane & 15;
    const int col0 = wvid*32 + ncol;          // t=0 column
    const int col1 = col0 + 16;               // t=1 column

    // ---- alpha gather for my sample: issue loads now, consume later ----
    T areg[8]; float afx, afy, afz;
    {
        float tv = TNEAR + (TFAR - TNEAR) * ((float)tid * (1.0f/(float)(NS-1)));
        Coords c = coords_n(o0 + d0*tv, o1 + d1*tv, o2 + d2*tv);
        afx = c.fx; afy = c.fy; afz = c.fz;
        const T* g = density + (u32)c.base;
        areg[0]=g[0]; areg[1]=g[1]; areg[2]=g[G]; areg[3]=g[G+1];
        areg[4]=g[G2]; areg[5]=g[G2+1]; areg[6]=g[G2+G]; areg[7]=g[G2+G+1];
    }

    // ---- W1/W0 fragments: registers for the whole kernel (one coalesced pass) ----
    short8 w1r[4][2];
    #pragma unroll
    for (int kq = 0; kq < 4; kq++) {
        w1r[kq][0] = *(const short8*)&w1g[W1F_IDX(kq, q, col0)];
        w1r[kq][1] = *(const short8*)&w1g[W1F_IDX(kq, q, col1)];
    }
    short8 w0r0 = {}, w0r1 = {};
    if (q < 2) {
        w0r0 = *(const short8*)&w0g[(col0 << 4) + q*8];
        w0r1 = *(const short8*)&w0g[(col1 << 4) + q*8];
    }

    // ---- gather role: 1 task/thread, 12 channels x 16 samples = 192 tasks ----
    const int gch = tid >> 4;                  // channel 0..15; active <12
    const int gs  = tid & 15;                  // sample-in-chunk
    const bool gact = (gch < K0DIM);
    const T* gbase = k0 + (size_t)(gact ? gch : 0) * G3;

    #define ISSUE(C0N, Q, FX, FY, FZ) do { if (gact) {                          \
        float tv_ = TNEAR + (TFAR-TNEAR)*((float)((C0N)+gs) * (1.0f/255.0f));   \
        Coords ce_ = coords_n(o0+d0*tv_, o1+d1*tv_, o2+d2*tv_);                 \
        FX = ce_.fx; FY = ce_.fy; FZ = ce_.fz;                                  \
        const T* g_ = gbase + (u32)ce_.base;                                    \
        Q[0]=g_[0]; Q[1]=g_[1]; Q[2]=g_[G]; Q[3]=g_[G+1];                       \
        Q[4]=g_[G2]; Q[5]=g_[G2+1]; Q[6]=g_[G2+G]; Q[7]=g_[G2+G+1];             \
    } } while(0)

    #define COMMIT(Q, FX, FY, FZ) do { if (gact) {                              \
        float z0_=tofl(Q[0]), z1_=tofl(Q[1]), z2_=tofl(Q[2]), z3_=tofl(Q[3]);   \
        float z4_=tofl(Q[4]), z5_=tofl(Q[5]), z6_=tofl(Q[6]), z7_=tofl(Q[7]);   \
        float c00_ = z0_ + (FZ)*(z1_-z0_);                                      \
        float c01_ = z2_ + (FZ)*(z3_-z2_);                                      \
        float c10_ = z4_ + (FZ)*(z5_-z4_);                                      \
        float c11_ = z6_ + (FZ)*(z7_-z6_);                                      \
        float e0_ = c00_ + (FY)*(c01_-c00_);                                    \
        float e1_ = c10_ + (FY)*(c11_-c10_);                                    \
        featB[gs*16 + gch] = f2bf(e0_ + (FX)*(e1_-e0_));                        \
    } } while(0)

    // depth-2 prefetch buffers
    T qa[8], qn[8];
    float fxa, fya, fza, fxn, fyn, fzn;
    ISSUE(0, qa, fxa, fya, fza);
    ISSUE(CHUNK, qn, fxn, fyn, fzn);

    // ---- stage small per-block tables into LDS ----
    for (int i = tid; i < CHUNK*4; i += 256)          // featB k=12..15 stays 0 forever
        featB[(i >> 2)*16 + 12 + (i & 3)] = 0;
    for (int k = tid; k < 3*WIDTH; k += 256) {
        int c = k >> 7, i = k & 127;
        W2Tf[k] = loadv(W2, i*3 + c);
    }
    if (tid < WIDTH) b1s[tid] = loadv(b1, tid);
    if (tid < 3)     b2s[tid] = loadv(b2, tid);

    // ---- view embedding (per-ray constant) ----
    if (tid < 27) {
        float inv = rsqrtf(d0*d0 + d1*d1 + d2*d2);
        float v0 = d0*inv, v1 = d1*inv, v2 = d2*inv;
        float val;
        if (tid < 3) {
            val = (tid == 0) ? v0 : ((tid == 1) ? v1 : v2);
        } else if (tid < 15) {
            int t2 = tid - 3; int dd = t2 >> 2; int p = t2 & 3;
            float vd = (dd == 0) ? v0 : ((dd == 1) ? v1 : v2);
            val = sinf(vd * (float)(1 << p));
        } else {
            int t2 = tid - 15; int dd = t2 >> 2; int p = t2 & 3;
            float vd = (dd == 0) ? v0 : ((dd == 1) ? v1 : v2);
            val = cosf(vd * (float)(1 << p));
        }
        vembs[tid] = val;
    }
    __syncthreads();

    // ---- base0 = b0 + vemb @ W0[12:39]  (per-ray) ----
    if (tid < WIDTH) {
        float a = loadv(b0, tid);
        #pragma unroll
        for (int i = 0; i < 27; i++)
            a += vembs[i] * loadv(W0, (K0DIM + i)*WIDTH + tid);
        base0[tid] = a;
    }

    // ---- finish alpha for my sample ----
    {
        float z0=tofl(areg[0]), z1=tofl(areg[1]), z2=tofl(areg[2]), z3=tofl(areg[3]);
        float z4=tofl(areg[4]), z5=tofl(areg[5]), z6=tofl(areg[6]), z7=tofl(areg[7]);
        float c00 = z0 + afz*(z1-z0);
        float c01 = z2 + afz*(z3-z2);
        float c10 = z4 + afz*(z5-z4);
        float c11 = z6 + afz*(z7-z6);
        float e0 = c00 + afy*(c01-c00);
        float e1 = c10 + afy*(c11-c10);
        float sigma = e0 + afx*(e1-e0);
        float alpha = 1.0f - rsqrtf(1.0f + __expf(sigma + ACT_SHIFT_F));
        wts[tid] = alpha;
    }
    __syncthreads();

    // ---- wave-parallel transmittance scan ----
    if (tid < 64) {
        const int l = tid;
        float a0 = wts[4*l+0], a1 = wts[4*l+1], a2 = wts[4*l+2], a3 = wts[4*l+3];
        float m0 = 1.0f - a0 + 1e-10f;
        float m1 = 1.0f - a1 + 1e-10f;
        float m2 = 1.0f - a2 + 1e-10f;
        float m3 = 1.0f - a3 + 1e-10f;
        float sc = (m0*m1)*(m2*m3);
        #pragma unroll
        for (int dlt = 1; dlt < 64; dlt <<= 1) {
            float o = __shfl_up(sc, dlt, 64);
            if (l >= dlt) sc *= o;
        }
        float Tr = __shfl_up(sc, 1, 64);
        if (l == 0) Tr = 1.0f;
        wts[4*l+0] = a0 * Tr; Tr *= m0;
        wts[4*l+1] = a1 * Tr; Tr *= m1;
        wts[4*l+2] = a2 * Tr; Tr *= m2;
        wts[4*l+3] = a3 * Tr; Tr *= m3;
        if (l == 63) ainvs = Tr;
    }
    __syncthreads();

    // ---- hoist per-thread constants out of the chunk loop ----
    const float bs00 = base0[col0], bs01 = base0[col1];
    const float b1c0 = b1s[col0],   b1c1 = b1s[col1];
    const float w200 = W2Tf[col0], w210 = W2Tf[WIDTH+col0], w220 = W2Tf[2*WIDTH+col0];
    const float w201 = W2Tf[col1], w211 = W2Tf[WIDTH+col1], w221 = W2Tf[2*WIDTH+col1];

    float rgbacc = 0.0f;

    #define CHUNK_BODY(Q, FX, FY, FZ, CI) do {                                       \
        COMMIT(Q, FX, FY, FZ);                                                       \
        __syncthreads();   /* A: featB ready */                                      \
        {   /* layer 0: h0[16][128] = relu(base0 + feat[16][12] @ W0) */             \
            short8 af0 = (short8){0,0,0,0,0,0,0,0};                                  \
            if (q < 2) af0 = *(const short8*)&featB[ncol*16 + q*8];                  \
            floatx4 a0_ = (floatx4){bs00, bs00, bs00, bs00};                         \
            floatx4 a1_ = (floatx4){bs01, bs01, bs01, bs01};                         \
            a0_ = __builtin_amdgcn_mfma_f32_16x16x32_bf16(af0, w0r0, a0_, 0, 0, 0);  \
            a1_ = __builtin_amdgcn_mfma_f32_16x16x32_bf16(af0, w0r1, a1_, 0, 0, 0);  \
            _Pragma("unroll")                                                        \
            for (int rI = 0; rI < 4; rI++) {                                         \
                h0B[(q*4+rI)*HBS + col0] = f2bf(fmaxf(a0_[rI], 0.0f));               \
                h0B[(q*4+rI)*HBS + col1] = f2bf(fmaxf(a1_[rI], 0.0f));               \
            }                                                                        \
        }                                                                            \
        __syncthreads();   /* B: h0B ready */                                        \
        if ((CI) + 2 < NCHUNK) ISSUE(((CI)+2)*CHUNK, Q, FX, FY, FZ);                 \
        {   /* layer 1 MFMA + fused layer 2 */                                       \
            floatx4 a0_ = (floatx4){b1c0, b1c0, b1c0, b1c0};                         \
            floatx4 a1_ = (floatx4){b1c1, b1c1, b1c1, b1c1};                         \
            _Pragma("unroll")                                                        \
            for (int kq = 0; kq < 4; kq++) {                                         \
                short8 af_ = *(const short8*)&h0B[ncol*HBS + kq*32 + q*8];           \
                a0_ = __builtin_amdgcn_mfma_f32_16x16x32_bf16(af_, w1r[kq][0], a0_, 0, 0, 0); \
                a1_ = __builtin_amdgcn_mfma_f32_16x16x32_bf16(af_, w1r[kq][1], a1_, 0, 0, 0); \
            }                                                                        \
            float p_[3][4];                                                          \
            _Pragma("unroll")                                                        \
            for (int rI = 0; rI < 4; rI++) {                                         \
                float h0_ = fmaxf(a0_[rI], 0.0f);                                    \
                float h1_ = fmaxf(a1_[rI], 0.0f);                                    \
                p_[0][rI] = h0_*w200 + h1_*w201;                                     \
                p_[1][rI] = h0_*w210 + h1_*w211;                                     \
                p_[2][rI] = h0_*w220 + h1_*w221;                                     \
            }                                                                        \
            _Pragma("unroll")                                                        \
            for (int m_ = 1; m_ <= 8; m_ <<= 1) {                                    \
                _Pragma("unroll")                                                    \
                for (int c_ = 0; c_ < 3; c_++) {                                     \
                    _Pragma("unroll")                                                \
                    for (int rI = 0; rI < 4; rI++)                                   \
                        p_[c_][rI] += __shfl_xor(p_[c_][rI], m_, 64);                \
                }                                                                    \
            }                                                                        \
            if (ncol == 0) {                                                         \
                _Pragma("unroll")                                                    \
                for (int rI = 0; rI < 4; rI++) {                                     \
                    _Pragma("unroll")                                                \
                    for (int c_ = 0; c_ < 3; c_++)                                   \
                        p2[(q*4+rI)*12 + wvid*3 + c_] = p_[c_][rI];                  \
                }                                                                    \
            }                                                                        \
        }                                                                            \
        __syncthreads();   /* C: p2 ready */                                         \
        if (tid < 48) {    /* sigmoid + weighted accumulate */                       \
            int c_ = tid >> 4, s_ = tid & 15;                                        \
            float x_ = b2s[c_] + p2[s_*12 + c_] + p2[s_*12 + 3 + c_]                 \
                     + p2[s_*12 + 6 + c_] + p2[s_*12 + 9 + c_];                      \
            float rgb_ = 1.0f / (1.0f + __expf(-x_));                                \
            rgbacc += wts[(CI)*CHUNK + s_] * rgb_;                                   \
        }                                                                            \
        /* no barrier: next featB/p2 writes are behind barriers A and B */           \
    } while(0)

    for (int cc = 0; cc < NCHUNK; cc += 2) {
        CHUNK_BODY(qa, fxa, fya, fza, cc);
        CHUNK_BODY(qn, fxn, fyn, fzn, cc + 1);
    }

    if (tid < 48) red[tid] = rgbacc;
    __syncthreads();
    if (tid < 3) {
        float s = 0.0f;
        #pragma unroll
        for (int k = 0; k < 16; k++) s += red[tid*16 + k];
        storev(out, r*3 + tid, s + ainvs);
    }
    #undef ISSUE
    #undef COMMIT
    #undef CHUNK_BODY
}

extern "C" void kernel_launch(void* const* d_in, const int* in_sizes, int n_in,
                              void* d_out, int out_size, void* d_ws, size_t ws_size,
                              hipStream_t stream) {
    int* mode = (int*)d_ws;
    u16* w1g = (u16*)((char*)d_ws + WS_W1G_OFF);
    u16* w0g = (u16*)((char*)d_ws + WS_W0G_OFF);

    decide_mode<<<dim3(1), dim3(64), 0, stream>>>((const u16*)d_in[1], mode);
    pack_weights<<<dim3(64), dim3(256), 0, stream>>>(d_in[6], d_in[4], w1g, w0g, mode);

    // bf16 interpretation
    dvgo_fused<u16, u16, 0><<<dim3(NRAYS), dim3(256), 0, stream>>>(
        (const u16*)d_in[0], (const u16*)d_in[1], (const u16*)d_in[2],
        (const u16*)d_in[3], (const u16*)d_in[4], (const u16*)d_in[5],
        (const u16*)d_in[6], (const u16*)d_in[7], (const u16*)d_in[8],
        (const u16*)d_in[9], w1g, w0g, (u16*)d_out, mode);

    // fp32 interpretation
    dvgo_fused<float, float, 1><<<dim3(NRAYS), dim3(256), 0, stream>>>(
        (const float*)d_in[0], (const float*)d_in[1], (const float*)d_in[2],
        (const float*)d_in[3], (const float*)d_in[4], (const float*)d_in[5],
        (const float*)d_in[6], (const float*)d_in[7], (const float*)d_in[8],
        (const float*)d_in[9], w1g, w0g, (float*)d_out, mode);
}

// Round 4
// 479.115 us; speedup vs baseline: 3.2174x; 1.1057x over previous
//
#include <hip/hip_runtime.h>
#include <hip/hip_bf16.h>

#define NRAYS 4096
#define NS 256
#define G 160
#define G2 (160*160)
#define G3 (160*160*160)
#define K0DIM 12
#define WIDTH 128
#define CHUNK 16
#define NCHUNK 16
#define HBS 136              // h-buffer bf16 row stride (272 B)
#define ACT_SHIFT_F (-4.5951198501345889f)
#define TNEAR 0.2f
#define TFAR 1.8f

// workspace: [0] mode; +1024 w1g (32768B); +33792 w0g (4096B); +65536 packed AoS grid (131.072 MB)
#define WS_W1G_OFF 1024
#define WS_W0G_OFF (1024 + 32768)
#define WS_PACK_OFF 65536
#define PACK_BYTES ((size_t)G3 * 16 * 2)
#define WS_NEED_AOS ((size_t)WS_PACK_OFF + PACK_BYTES)

typedef unsigned short u16;
typedef unsigned int u32;
typedef __attribute__((ext_vector_type(8))) short short8;   // 8 bf16 = 4 VGPRs (MFMA A/B frag)
typedef __attribute__((ext_vector_type(4))) float floatx4;  // MFMA C/D frag

// W1G[kq][qsub][col][j]: B-frag for (kq, quarter qsub, output col) = 16 contiguous bytes
#define W1F_IDX(kq, qs, n) (((((kq)<<2) + (qs)) * 128 + (n)) << 3)

__device__ __forceinline__ float bf2f(u16 u) {
    union { u32 i; float f; } v; v.i = ((u32)u) << 16; return v.f;
}
__device__ __forceinline__ u16 f2bf(float f) {   // RTNE fp32 -> bf16
    union { float f; u32 u; } v; v.f = f;
    u32 r = v.u + 0x7FFFu + ((v.u >> 16) & 1u);
    return (u16)(r >> 16);
}

__device__ __forceinline__ float loadv(const float* p, int i) { return p[i]; }
__device__ __forceinline__ float loadv(const u16* p, int i)   { return bf2f(p[i]); }
__device__ __forceinline__ void storev(float* p, int i, float v) { p[i] = v; }
__device__ __forceinline__ void storev(u16* p, int i, float v)   { p[i] = f2bf(v); }
__device__ __forceinline__ float tofl(float v) { return v; }
__device__ __forceinline__ float tofl(u16 v)   { return bf2f(v); }
__device__ __forceinline__ float ldm(const void* p, int i, int mode) {
    return mode ? ((const float*)p)[i] : bf2f(((const u16*)p)[i]);
}

struct Coords { int base; float fx, fy, fz; };

__device__ __forceinline__ Coords coords_n(float px, float py, float pz) {
    float gx = fminf(fmaxf((px + 1.0f) * 79.5f, 0.0f), 159.0f);
    float gy = fminf(fmaxf((py + 1.0f) * 79.5f, 0.0f), 159.0f);
    float gz = fminf(fmaxf((pz + 1.0f) * 79.5f, 0.0f), 159.0f);
    int ix = (int)gx; if (ix > 158) ix = 158;
    int iy = (int)gy; if (iy > 158) iy = 158;
    int iz = (int)gz; if (iz > 158) iz = 158;
    Coords c;
    c.base = (ix * G + iy) * G + iz;
    c.fx = gx - (float)ix; c.fy = gy - (float)iy; c.fz = gz - (float)iz;
    return c;
}

// mode: 0 = buffers hold bf16, 1 = buffers hold fp32.  Parallel version (~2us, was 30us serial).
__global__ void decide_mode(const u16* __restrict__ rays_d_u16, int* __restrict__ mode) {
    __shared__ int cnt;
    if (threadIdx.x == 0) cnt = 0;
    __syncthreads();
    if (threadIdx.x < 128) {
        u16 u = rays_d_u16[threadIdx.x];
        int e = (u >> 7) & 0xFF;
        int m = u & 0x7F;
        float v = bf2f(u);
        if (e == 0xFF || (e == 0 && m != 0) || fabsf(v) > 32.0f) atomicAdd(&cnt, 1);
    }
    __syncthreads();
    if (threadIdx.x == 0) *mode = (cnt >= 4) ? 1 : 0;
}

// pre-pack W1 (frag-swizzled) and W0T (zero-padded K=16) into workspace, bf16.
__global__ void pack_weights(const void* __restrict__ W1, const void* __restrict__ W0,
                             u16* __restrict__ w1g, u16* __restrict__ w0g,
                             const int* __restrict__ mode) {
    const int m = *mode;
    const int idx = blockIdx.x * 256 + threadIdx.x;
    for (int i = idx; i < WIDTH * WIDTH; i += 64 * 256) {
        int k = i >> 7, n = i & 127;
        float v = m ? ((const float*)W1)[i] : bf2f(((const u16*)W1)[i]);
        w1g[W1F_IDX(k >> 5, (k >> 3) & 3, n) + (k & 7)] = f2bf(v);
    }
    for (int i = idx; i < WIDTH * 16; i += 64 * 256) {
        int n = i >> 4, k = i & 15;
        float v = 0.0f;
        if (k < K0DIM) v = m ? ((const float*)W0)[k * WIDTH + n] : bf2f(((const u16*)W0)[k * WIDTH + n]);
        w0g[i] = f2bf(v);
    }
}

// one-time AoS repack: packed[vox][c] bf16, c0..11 = k0, c12 = density, c13..15 = 0.
// One corner-pair (z,z+1) = 64B contiguous, 16B-aligned.
__global__ __launch_bounds__(256)
void repack_grid(const void* __restrict__ density, const void* __restrict__ k0,
                 u16* __restrict__ packed, const int* __restrict__ modep) {
    const int mode = *modep;
    const u32 vox = (u32)blockIdx.x * 128u + (u32)(threadIdx.x & 127);
    const int h = threadIdx.x >> 7;
    u16 o[8];
    if (mode) {
        const float* kf = (const float*)k0;
        const float* df = (const float*)density;
        if (h == 0) {
            #pragma unroll
            for (int c = 0; c < 8; c++) o[c] = f2bf(kf[(size_t)c*G3 + vox]);
        } else {
            #pragma unroll
            for (int c = 0; c < 4; c++) o[c] = f2bf(kf[(size_t)(8+c)*G3 + vox]);
            o[4] = f2bf(df[vox]); o[5] = 0; o[6] = 0; o[7] = 0;
        }
    } else {
        const u16* ku = (const u16*)k0;
        const u16* du = (const u16*)density;
        if (h == 0) {
            #pragma unroll
            for (int c = 0; c < 8; c++) o[c] = ku[(size_t)c*G3 + vox];
        } else {
            #pragma unroll
            for (int c = 0; c < 4; c++) o[c] = ku[(size_t)(8+c)*G3 + vox];
            o[4] = du[vox]; o[5] = 0; o[6] = 0; o[7] = 0;
        }
    }
    short8 ov;
    #pragma unroll
    for (int j = 0; j < 8; j++) ov[j] = (short)o[j];
    *(short8*)(packed + (size_t)vox*16 + (size_t)h*8) = ov;
}

// ================== new main kernel: AoS gather, runtime mode ==================
__global__ __launch_bounds__(256, 4)
void dvgo_aos(const void* __restrict__ rays_o, const void* __restrict__ rays_d,
              const void* __restrict__ W0, const void* __restrict__ b0,
              const void* __restrict__ b1, const void* __restrict__ W2,
              const void* __restrict__ b2,
              const u16* __restrict__ packed, const u16* __restrict__ w1g,
              const u16* __restrict__ w0g, void* __restrict__ out,
              const int* __restrict__ modep)
{
    const int mode = *modep;

    __shared__ __align__(16) u16   featB[64 * 16];   // 2048 B  feat bf16 [sample][k<=15]
    __shared__ __align__(16) u16   h0B[16 * HBS];    // 4352 B
    __shared__ __align__(16) u16   h1B[16 * HBS];    // 4352 B
    __shared__ float p2[4 * 16 * 12];                // 3072 B  [tile][s][wave][c]
    __shared__ float rgbs[NS * 3];                   // 3072 B
    __shared__ float wts[NS];                        // 1024 B
    __shared__ float base0[WIDTH];
    __shared__ float vembs[27];
    __shared__ float ainvs;

    const int r = blockIdx.x;
    const int tid = threadIdx.x;

    const float o0 = ldm(rays_o, r*3+0, mode);
    const float o1 = ldm(rays_o, r*3+1, mode);
    const float o2 = ldm(rays_o, r*3+2, mode);
    const float d0 = ldm(rays_d, r*3+0, mode);
    const float d1 = ldm(rays_d, r*3+1, mode);
    const float d2 = ldm(rays_d, r*3+2, mode);

    // ---- role constants ----
    const int lane = tid & 63;
    const int wvid = tid >> 6;
    const int q    = lane >> 4;
    const int ncol = lane & 15;
    const int col0 = wvid*32 + ncol;
    const int col1 = col0 + 16;

    // gather role: 4 threads per sample (corner dx,dy); 64 samples per macro-chunk
    const int sm  = tid >> 2;
    const int gdy = tid & 1;
    const int gdx = (tid >> 1) & 1;
    const u32 coff = (u32)(gdx*G2 + gdy*G) * 16u;

    float gfx, gfy, gfz;
    short8 qg[4];

    #define ISSUE_G(C0N) do {                                                     \
        float tv_ = TNEAR + (TFAR-TNEAR)*((float)((C0N)+sm) * (1.0f/255.0f));     \
        Coords ce_ = coords_n(o0+d0*tv_, o1+d1*tv_, o2+d2*tv_);                   \
        gfx = ce_.fx; gfy = ce_.fy; gfz = ce_.fz;                                 \
        const u16* g_ = packed + ((u32)ce_.base*16u + coff);                      \
        qg[0] = *(const short8*)(g_);                                             \
        qg[1] = *(const short8*)(g_ + 8);                                         \
        qg[2] = *(const short8*)(g_ + 16);                                        \
        qg[3] = *(const short8*)(g_ + 24);                                        \
    } while(0)

    #define COMMIT_G(C0N) do {                                                    \
        float wxy_ = (gdx ? gfx : 1.0f-gfx) * (gdy ? gfy : 1.0f-gfy);             \
        float v_[13];                                                             \
        _Pragma("unroll")                                                         \
        for (int c_ = 0; c_ < 8; c_++) {                                          \
            float lo_ = bf2f((u16)qg[0][c_]);                                     \
            float hi_ = bf2f((u16)qg[2][c_]);                                     \
            v_[c_] = (lo_ + gfz*(hi_-lo_)) * wxy_;                                \
        }                                                                         \
        _Pragma("unroll")                                                         \
        for (int c_ = 0; c_ < 5; c_++) {                                          \
            float lo_ = bf2f((u16)qg[1][c_]);                                     \
            float hi_ = bf2f((u16)qg[3][c_]);                                     \
            v_[8+c_] = (lo_ + gfz*(hi_-lo_)) * wxy_;                              \
        }                                                                         \
        _Pragma("unroll")                                                         \
        for (int c_ = 0; c_ < 13; c_++) {                                         \
            v_[c_] += __shfl_xor(v_[c_], 1, 64);                                  \
            v_[c_] += __shfl_xor(v_[c_], 2, 64);                                  \
        }                                                                         \
        if ((tid & 3) == 0) {                                                     \
            _Pragma("unroll")                                                     \
            for (int c_ = 0; c_ < 6; c_++) {                                      \
                u32 pk_ = (u32)f2bf(v_[2*c_]) | ((u32)f2bf(v_[2*c_+1]) << 16);    \
                *(u32*)&featB[sm*16 + 2*c_] = pk_;                                \
            }                                                                     \
            float alpha_ = 1.0f - rsqrtf(1.0f + __expf(v_[12] + ACT_SHIFT_F));    \
            wts[(C0N) + sm] = alpha_;                                             \
        }                                                                         \
    } while(0)

    ISSUE_G(0);   // start chunk-0 gathers ASAP

    // ---- W1/W0/W2 fragments: registers for the whole kernel ----
    short8 w1r[4][2];
    #pragma unroll
    for (int kq = 0; kq < 4; kq++) {
        w1r[kq][0] = *(const short8*)&w1g[W1F_IDX(kq, q, col0)];
        w1r[kq][1] = *(const short8*)&w1g[W1F_IDX(kq, q, col1)];
    }
    short8 w0r0 = {}, w0r1 = {};
    if (q < 2) {
        w0r0 = *(const short8*)&w0g[(col0 << 4) + q*8];
        w0r1 = *(const short8*)&w0g[(col1 << 4) + q*8];
    }
    short8 w2r;
    #pragma unroll
    for (int j = 0; j < 8; j++) {
        u16 t_ = 0;
        if (ncol < 3) t_ = f2bf(ldm(W2, (wvid*32 + q*8 + j)*3 + ncol, mode));
        w2r[j] = (short)t_;
    }
    const float b2v = (ncol < 3) ? ldm(b2, ncol, mode) : 0.0f;
    const float b1c0 = ldm(b1, col0, mode);
    const float b1c1 = ldm(b1, col1, mode);

    // featB cols 12..15 stay zero forever
    for (int i = tid; i < 64*4; i += 256)
        featB[(i >> 2)*16 + 12 + (i & 3)] = 0;

    // ---- view embedding ----
    if (tid < 27) {
        float inv = rsqrtf(d0*d0 + d1*d1 + d2*d2);
        float v0 = d0*inv, v1 = d1*inv, v2 = d2*inv;
        float val;
        if (tid < 3) {
            val = (tid == 0) ? v0 : ((tid == 1) ? v1 : v2);
        } else if (tid < 15) {
            int t2 = tid - 3; int dd = t2 >> 2; int p = t2 & 3;
            float vd = (dd == 0) ? v0 : ((dd == 1) ? v1 : v2);
            val = sinf(vd * (float)(1 << p));
        } else {
            int t2 = tid - 15; int dd = t2 >> 2; int p = t2 & 3;
            float vd = (dd == 0) ? v0 : ((dd == 1) ? v1 : v2);
            val = cosf(vd * (float)(1 << p));
        }
        vembs[tid] = val;
    }
    __syncthreads();

    // ---- base0 = b0 + vemb @ W0[12:39] ----
    if (tid < WIDTH) {
        float a = ldm(b0, tid, mode);
        #pragma unroll
        for (int i = 0; i < 27; i++)
            a += vembs[i] * ldm(W0, (K0DIM + i)*WIDTH + tid, mode);
        base0[tid] = a;
    }
    __syncthreads();

    const float bs00 = base0[col0], bs01 = base0[col1];

    // ================== main loop: 4 macro-chunks x 4 tiles ==================
    for (int mi = 0; mi < 4; mi++) {
        COMMIT_G(mi*64);
        if (mi < 3) ISSUE_G((mi+1)*64);     // depth-1 prefetch: window = 12 barriers of compute
        __syncthreads();                     // A: featB[64] ready

        for (int ti = 0; ti < 4; ti++) {
            // (b) layer 0: h0[16][128] = relu(base0 + feat[16][12] @ W0)
            short8 af0 = (short8){0,0,0,0,0,0,0,0};
            if (q < 2) af0 = *(const short8*)&featB[(ti*16 + ncol)*16 + q*8];
            floatx4 a0 = (floatx4){bs00,bs00,bs00,bs00};
            floatx4 a1 = (floatx4){bs01,bs01,bs01,bs01};
            a0 = __builtin_amdgcn_mfma_f32_16x16x32_bf16(af0, w0r0, a0, 0, 0, 0);
            a1 = __builtin_amdgcn_mfma_f32_16x16x32_bf16(af0, w0r1, a1, 0, 0, 0);
            #pragma unroll
            for (int rI = 0; rI < 4; rI++) {
                h0B[(q*4+rI)*HBS + col0] = f2bf(fmaxf(a0[rI], 0.0f));
                h0B[(q*4+rI)*HBS + col1] = f2bf(fmaxf(a1[rI], 0.0f));
            }
            __syncthreads();                 // B1: h0B ready

            // (c1) layer 1 -> h1B
            floatx4 c0a = (floatx4){b1c0,b1c0,b1c0,b1c0};
            floatx4 c1a = (floatx4){b1c1,b1c1,b1c1,b1c1};
            #pragma unroll
            for (int kq = 0; kq < 4; kq++) {
                short8 af = *(const short8*)&h0B[ncol*HBS + kq*32 + q*8];
                c0a = __builtin_amdgcn_mfma_f32_16x16x32_bf16(af, w1r[kq][0], c0a, 0, 0, 0);
                c1a = __builtin_amdgcn_mfma_f32_16x16x32_bf16(af, w1r[kq][1], c1a, 0, 0, 0);
            }
            #pragma unroll
            for (int rI = 0; rI < 4; rI++) {
                h1B[(q*4+rI)*HBS + col0] = f2bf(fmaxf(c0a[rI], 0.0f));
                h1B[(q*4+rI)*HBS + col1] = f2bf(fmaxf(c1a[rI], 0.0f));
            }
            __syncthreads();                 // B2: h1B ready

            // (c2) layer 2 via MFMA: each wave does its K=32 slice
            short8 af2 = *(const short8*)&h1B[ncol*HBS + wvid*32 + q*8];
            floatx4 pp = (floatx4){0.0f,0.0f,0.0f,0.0f};
            if (wvid == 0 && ncol < 3) pp = (floatx4){b2v,b2v,b2v,b2v};
            pp = __builtin_amdgcn_mfma_f32_16x16x32_bf16(af2, w2r, pp, 0, 0, 0);
            if (ncol < 3) {
                #pragma unroll
                for (int rI = 0; rI < 4; rI++)
                    p2[ti*192 + (q*4+rI)*12 + wvid*3 + ncol] = pp[rI];
            }
            __syncthreads();                 // C: p2 ready

            // (d) sigmoid -> staged rgb (weights applied after the scan)
            if (tid < 48) {
                int c_ = tid >> 4, s_ = tid & 15;
                int pb = ti*192 + s_*12;
                float x = p2[pb + c_] + p2[pb + 3 + c_] + p2[pb + 6 + c_] + p2[pb + 9 + c_];
                rgbs[(mi*64 + ti*16 + s_)*3 + c_] = 1.0f / (1.0f + __expf(-x));
            }
            // no extra barrier: next writers (h0B/h1B/p2/featB) are all behind B1/B2/C/A
        }
    }

    __syncthreads();   // rgbs + wts complete

    // ---- wave-parallel transmittance scan ----
    if (tid < 64) {
        const int l = tid;
        float a0 = wts[4*l+0], a1 = wts[4*l+1], a2 = wts[4*l+2], a3 = wts[4*l+3];
        float m0 = 1.0f - a0 + 1e-10f;
        float m1 = 1.0f - a1 + 1e-10f;
        float m2 = 1.0f - a2 + 1e-10f;
        float m3 = 1.0f - a3 + 1e-10f;
        float sc = (m0*m1)*(m2*m3);
        #pragma unroll
        for (int dlt = 1; dlt < 64; dlt <<= 1) {
            float o = __shfl_up(sc, dlt, 64);
            if (l >= dlt) sc *= o;
        }
        float Tr = __shfl_up(sc, 1, 64);
        if (l == 0) Tr = 1.0f;
        wts[4*l+0] = a0 * Tr; Tr *= m0;
        wts[4*l+1] = a1 * Tr; Tr *= m1;
        wts[4*l+2] = a2 * Tr; Tr *= m2;
        wts[4*l+3] = a3 * Tr; Tr *= m3;
        if (l == 63) ainvs = Tr;
    }
    __syncthreads();

    // ---- weighted reduce: wave w (<3) owns channel w ----
    if (wvid < 3) {
        float a = 0.0f;
        #pragma unroll
        for (int j = 0; j < 4; j++) {
            int s = lane*4 + j;
            a += wts[s] * rgbs[s*3 + wvid];
        }
        #pragma unroll
        for (int m = 1; m <= 32; m <<= 1) a += __shfl_xor(a, m, 64);
        if (lane == 0) {
            float v = a + ainvs;
            if (mode) ((float*)out)[r*3 + wvid] = v;
            else      ((u16*)out)[r*3 + wvid]   = f2bf(v);
        }
    }
    #undef ISSUE_G
    #undef COMMIT_G
}

// ================== fallback (round-3 kernel, verbatim): used if ws too small ==================
template <typename T, typename OT, int MODE>
__global__ __launch_bounds__(256, 4)
void dvgo_fb(const T* __restrict__ rays_o, const T* __restrict__ rays_d,
             const T* __restrict__ density, const T* __restrict__ k0,
             const T* __restrict__ W0, const T* __restrict__ b0,
             const T* __restrict__ W1, const T* __restrict__ b1,
             const T* __restrict__ W2, const T* __restrict__ b2,
             const u16* __restrict__ w1g, const u16* __restrict__ w0g,
             OT* __restrict__ out, const int* __restrict__ mode)
{
    if (*mode != MODE) return;

    __shared__ __align__(16) u16   h0B[CHUNK * HBS];
    __shared__ __align__(16) u16   featB[CHUNK * 16];
    __shared__ __align__(16) float W2Tf[3 * WIDTH];
    __shared__ float p2[CHUNK * 12];
    __shared__ float base0[WIDTH];
    __shared__ float b1s[WIDTH];
    __shared__ float b2s[3];
    __shared__ float vembs[27];
    __shared__ float wts[NS];
    __shared__ float red[48];
    __shared__ float ainvs;

    const int r = blockIdx.x;
    const int tid = threadIdx.x;

    const float o0 = loadv(rays_o, r*3+0);
    const float o1 = loadv(rays_o, r*3+1);
    const float o2 = loadv(rays_o, r*3+2);
    const float d0 = loadv(rays_d, r*3+0);
    const float d1 = loadv(rays_d, r*3+1);
    const float d2 = loadv(rays_d, r*3+2);

    const int lane = tid & 63;
    const int wvid = tid >> 6;
    const int q    = lane >> 4;
    const int ncol = lane & 15;
    const int col0 = wvid*32 + ncol;
    const int col1 = col0 + 16;

    T areg[8]; float afx, afy, afz;
    {
        float tv = TNEAR + (TFAR - TNEAR) * ((float)tid * (1.0f/(float)(NS-1)));
        Coords c = coords_n(o0 + d0*tv, o1 + d1*tv, o2 + d2*tv);
        afx = c.fx; afy = c.fy; afz = c.fz;
        const T* g = density + (u32)c.base;
        areg[0]=g[0]; areg[1]=g[1]; areg[2]=g[G]; areg[3]=g[G+1];
        areg[4]=g[G2]; areg[5]=g[G2+1]; areg[6]=g[G2+G]; areg[7]=g[G2+G+1];
    }

    short8 w1r[4][2];
    #pragma unroll
    for (int kq = 0; kq < 4; kq++) {
        w1r[kq][0] = *(const short8*)&w1g[W1F_IDX(kq, q, col0)];
        w1r[kq][1] = *(const short8*)&w1g[W1F_IDX(kq, q, col1)];
    }
    short8 w0r0 = {}, w0r1 = {};
    if (q < 2) {
        w0r0 = *(const short8*)&w0g[(col0 << 4) + q*8];
        w0r1 = *(const short8*)&w0g[(col1 << 4) + q*8];
    }

    const int gch = tid >> 4;
    const int gs  = tid & 15;
    const bool gact = (gch < K0DIM);
    const T* gbase = k0 + (size_t)(gact ? gch : 0) * G3;

    #define ISSUE(C0N, Q, FX, FY, FZ) do { if (gact) {                          \
        float tv_ = TNEAR + (TFAR-TNEAR)*((float)((C0N)+gs) * (1.0f/255.0f));   \
        Coords ce_ = coords_n(o0+d0*tv_, o1+d1*tv_, o2+d2*tv_);                 \
        FX = ce_.fx; FY = ce_.fy; FZ = ce_.fz;                                  \
        const T* g_ = gbase + (u32)ce_.base;                                    \
        Q[0]=g_[0]; Q[1]=g_[1]; Q[2]=g_[G]; Q[3]=g_[G+1];                       \
        Q[4]=g_[G2]; Q[5]=g_[G2+1]; Q[6]=g_[G2+G]; Q[7]=g_[G2+G+1];             \
    } } while(0)

    #define COMMIT(Q, FX, FY, FZ) do { if (gact) {                              \
        float z0_=tofl(Q[0]), z1_=tofl(Q[1]), z2_=tofl(Q[2]), z3_=tofl(Q[3]);   \
        float z4_=tofl(Q[4]), z5_=tofl(Q[5]), z6_=tofl(Q[6]), z7_=tofl(Q[7]);   \
        float c00_ = z0_ + (FZ)*(z1_-z0_);                                      \
        float c01_ = z2_ + (FZ)*(z3_-z2_);                                      \
        float c10_ = z4_ + (FZ)*(z5_-z4_);                                      \
        float c11_ = z6_ + (FZ)*(z7_-z6_);                                      \
        float e0_ = c00_ + (FY)*(c01_-c00_);                                    \
        float e1_ = c10_ + (FY)*(c11_-c10_);                                    \
        featB[gs*16 + gch] = f2bf(e0_ + (FX)*(e1_-e0_));                        \
    } } while(0)

    T qa[8], qn[8];
    float fxa, fya, fza, fxn, fyn, fzn;
    ISSUE(0, qa, fxa, fya, fza);
    ISSUE(CHUNK, qn, fxn, fyn, fzn);

    for (int i = tid; i < CHUNK*4; i += 256)
        featB[(i >> 2)*16 + 12 + (i & 3)] = 0;
    for (int k = tid; k < 3*WIDTH; k += 256) {
        int c = k >> 7, i = k & 127;
        W2Tf[k] = loadv(W2, i*3 + c);
    }
    if (tid < WIDTH) b1s[tid] = loadv(b1, tid);
    if (tid < 3)     b2s[tid] = loadv(b2, tid);

    if (tid < 27) {
        float inv = rsqrtf(d0*d0 + d1*d1 + d2*d2);
        float v0 = d0*inv, v1 = d1*inv, v2 = d2*inv;
        float val;
        if (tid < 3) {
            val = (tid == 0) ? v0 : ((tid == 1) ? v1 : v2);
        } else if (tid < 15) {
            int t2 = tid - 3; int dd = t2 >> 2; int p = t2 & 3;
            float vd = (dd == 0) ? v0 : ((dd == 1) ? v1 : v2);
            val = sinf(vd * (float)(1 << p));
        } else {
            int t2 = tid - 15; int dd = t2 >> 2; int p = t2 & 3;
            float vd = (dd == 0) ? v0 : ((dd == 1) ? v1 : v2);
            val = cosf(vd * (float)(1 << p));
        }
        vembs[tid] = val;
    }
    __syncthreads();

    if (tid < WIDTH) {
        float a = loadv(b0, tid);
        #pragma unroll
        for (int i = 0; i < 27; i++)
            a += vembs[i] * loadv(W0, (K0DIM + i)*WIDTH + tid);
        base0[tid] = a;
    }

    {
        float z0=tofl(areg[0]), z1=tofl(areg[1]), z2=tofl(areg[2]), z3=tofl(areg[3]);
        float z4=tofl(areg[4]), z5=tofl(areg[5]), z6=tofl(areg[6]), z7=tofl(areg[7]);
        float c00 = z0 + afz*(z1-z0);
        float c01 = z2 + afz*(z3-z2);
        float c10 = z4 + afz*(z5-z4);
        float c11 = z6 + afz*(z7-z6);
        float e0 = c00 + afy*(c01-c00);
        float e1 = c10 + afy*(c11-c10);
        float sigma = e0 + afx*(e1-e0);
        float alpha = 1.0f - rsqrtf(1.0f + __expf(sigma + ACT_SHIFT_F));
        wts[tid] = alpha;
    }
    __syncthreads();

    if (tid < 64) {
        const int l = tid;
        float a0 = wts[4*l+0], a1 = wts[4*l+1], a2 = wts[4*l+2], a3 = wts[4*l+3];
        float m0 = 1.0f - a0 + 1e-10f;
        float m1 = 1.0f - a1 + 1e-10f;
        float m2 = 1.0f - a2 + 1e-10f;
        float m3 = 1.0f - a3 + 1e-10f;
        float sc = (m0*m1)*(m2*m3);
        #pragma unroll
        for (int dlt = 1; dlt < 64; dlt <<= 1) {
            float o = __shfl_up(sc, dlt, 64);
            if (l >= dlt) sc *= o;
        }
        float Tr = __shfl_up(sc, 1, 64);
        if (l == 0) Tr = 1.0f;
        wts[4*l+0] = a0 * Tr; Tr *= m0;
        wts[4*l+1] = a1 * Tr; Tr *= m1;
        wts[4*l+2] = a2 * Tr; Tr *= m2;
        wts[4*l+3] = a3 * Tr; Tr *= m3;
        if (l == 63) ainvs = Tr;
    }
    __syncthreads();

    const float bs00 = base0[col0], bs01 = base0[col1];
    const float b1c0 = b1s[col0],   b1c1 = b1s[col1];
    const float w200 = W2Tf[col0], w210 = W2Tf[WIDTH+col0], w220 = W2Tf[2*WIDTH+col0];
    const float w201 = W2Tf[col1], w211 = W2Tf[WIDTH+col1], w221 = W2Tf[2*WIDTH+col1];

    float rgbacc = 0.0f;

    #define CHUNK_BODY(Q, FX, FY, FZ, CI) do {                                       \
        COMMIT(Q, FX, FY, FZ);                                                       \
        __syncthreads();                                                             \
        {                                                                            \
            short8 af0 = (short8){0,0,0,0,0,0,0,0};                                  \
            if (q < 2) af0 = *(const short8*)&featB[ncol*16 + q*8];                  \
            floatx4 a0_ = (floatx4){bs00, bs00, bs00, bs00};                         \
            floatx4 a1_ = (floatx4){bs01, bs01, bs01, bs01};                         \
            a0_ = __builtin_amdgcn_mfma_f32_16x16x32_bf16(af0, w0r0, a0_, 0, 0, 0);  \
            a1_ = __builtin_amdgcn_mfma_f32_16x16x32_bf16(af0, w0r1, a1_, 0, 0, 0);  \
            _Pragma("unroll")                                                        \
            for (int rI = 0; rI < 4; rI++) {                                         \
                h0B[(q*4+rI)*HBS + col0] = f2bf(fmaxf(a0_[rI], 0.0f));               \
                h0B[(q*4+rI)*HBS + col1] = f2bf(fmaxf(a1_[rI], 0.0f));               \
            }                                                                        \
        }                                                                            \
        __syncthreads();                                                             \
        if ((CI) + 2 < NCHUNK) ISSUE(((CI)+2)*CHUNK, Q, FX, FY, FZ);                 \
        {                                                                            \
            floatx4 a0_ = (floatx4){b1c0, b1c0, b1c0, b1c0};                         \
            floatx4 a1_ = (floatx4){b1c1, b1c1, b1c1, b1c1};                         \
            _Pragma("unroll")                                                        \
            for (int kq = 0; kq < 4; kq++) {                                         \
                short8 af_ = *(const short8*)&h0B[ncol*HBS + kq*32 + q*8];           \
                a0_ = __builtin_amdgcn_mfma_f32_16x16x32_bf16(af_, w1r[kq][0], a0_, 0, 0, 0); \
                a1_ = __builtin_amdgcn_mfma_f32_16x16x32_bf16(af_, w1r[kq][1], a1_, 0, 0, 0); \
            }                                                                        \
            float p_[3][4];                                                          \
            _Pragma("unroll")                                                        \
            for (int rI = 0; rI < 4; rI++) {                                         \
                float h0_ = fmaxf(a0_[rI], 0.0f);                                    \
                float h1_ = fmaxf(a1_[rI], 0.0f);                                    \
                p_[0][rI] = h0_*w200 + h1_*w201;                                     \
                p_[1][rI] = h0_*w210 + h1_*w211;                                     \
                p_[2][rI] = h0_*w220 + h1_*w221;                                     \
            }                                                                        \
            _Pragma("unroll")                                                        \
            for (int m_ = 1; m_ <= 8; m_ <<= 1) {                                    \
                _Pragma("unroll")                                                    \
                for (int c_ = 0; c_ < 3; c_++) {                                     \
                    _Pragma("unroll")                                                \
                    for (int rI = 0; rI < 4; rI++)                                   \
                        p_[c_][rI] += __shfl_xor(p_[c_][rI], m_, 64);                \
                }                                                                    \
            }                                                                        \
            if (ncol == 0) {                                                         \
                _Pragma("unroll")                                                    \
                for (int rI = 0; rI < 4; rI++) {                                     \
                    _Pragma("unroll")                                                \
                    for (int c_ = 0; c_ < 3; c_++)                                   \
                        p2[(q*4+rI)*12 + wvid*3 + c_] = p_[c_][rI];                  \
                }                                                                    \
            }                                                                        \
        }                                                                            \
        __syncthreads();                                                             \
        if (tid < 48) {                                                              \
            int c_ = tid >> 4, s_ = tid & 15;                                        \
            float x_ = b2s[c_] + p2[s_*12 + c_] + p2[s_*12 + 3 + c_]                 \
                     + p2[s_*12 + 6 + c_] + p2[s_*12 + 9 + c_];                      \
            float rgb_ = 1.0f / (1.0f + __expf(-x_));                                \
            rgbacc += wts[(CI)*CHUNK + s_] * rgb_;                                   \
        }                                                                            \
    } while(0)

    for (int cc = 0; cc < NCHUNK; cc += 2) {
        CHUNK_BODY(qa, fxa, fya, fza, cc);
        CHUNK_BODY(qn, fxn, fyn, fzn, cc + 1);
    }

    if (tid < 48) red[tid] = rgbacc;
    __syncthreads();
    if (tid < 3) {
        float s = 0.0f;
        #pragma unroll
        for (int k = 0; k < 16; k++) s += red[tid*16 + k];
        storev(out, r*3 + tid, s + ainvs);
    }
    #undef ISSUE
    #undef COMMIT
    #undef CHUNK_BODY
}

extern "C" void kernel_launch(void* const* d_in, const int* in_sizes, int n_in,
                              void* d_out, int out_size, void* d_ws, size_t ws_size,
                              hipStream_t stream) {
    int* mode = (int*)d_ws;
    u16* w1g = (u16*)((char*)d_ws + WS_W1G_OFF);
    u16* w0g = (u16*)((char*)d_ws + WS_W0G_OFF);

    decide_mode<<<dim3(1), dim3(128), 0, stream>>>((const u16*)d_in[1], mode);
    pack_weights<<<dim3(64), dim3(256), 0, stream>>>(d_in[6], d_in[4], w1g, w0g, mode);

    if (ws_size >= WS_NEED_AOS) {
        u16* packed = (u16*)((char*)d_ws + WS_PACK_OFF);
        repack_grid<<<dim3(G3/128), dim3(256), 0, stream>>>(d_in[2], d_in[3], packed, mode);
        dvgo_aos<<<dim3(NRAYS), dim3(256), 0, stream>>>(
            d_in[0], d_in[1], d_in[4], d_in[5], d_in[7], d_in[8], d_in[9],
            packed, w1g, w0g, d_out, mode);
    } else {
        // fallback: round-3 path (no repack workspace)
        dvgo_fb<u16, u16, 0><<<dim3(NRAYS), dim3(256), 0, stream>>>(
            (const u16*)d_in[0], (const u16*)d_in[1], (const u16*)d_in[2],
            (const u16*)d_in[3], (const u16*)d_in[4], (const u16*)d_in[5],
            (const u16*)d_in[6], (const u16*)d_in[7], (const u16*)d_in[8],
            (const u16*)d_in[9], w1g, w0g, (u16*)d_out, mode);
        dvgo_fb<float, float, 1><<<dim3(NRAYS), dim3(256), 0, stream>>>(
            (const float*)d_in[0], (const float*)d_in[1], (const float*)d_in[2],
            (const float*)d_in[3], (const float*)d_in[4], (const float*)d_in[5],
            (const float*)d_in[6], (const float*)d_in[7], (const float*)d_in[8],
            (const float*)d_in[9], w1g, w0g, (float*)d_out, mode);
    }
}